// Round 11
// baseline (310.508 us; speedup 1.0000x reference)
//
#include <hip/hip_runtime.h>
#include <math.h>

#define NBINS 15
#define NCLS  100
#define NHALF 50               // float2 slots per row (2 classes per lane)
#define NSEG  (NBINS * NCLS)   // 1500
#define R     4                // rows per wave per iteration (ILP batching)

// DPP-based wave64 sum on the VALU pipe (no DS ops). ctrl must be literal.
template <int CTRL>
__device__ __forceinline__ float dpp_add_f32(float x) {
    int y = __builtin_amdgcn_update_dpp(0, __float_as_int(x), CTRL, 0xf, 0xf, true);
    return x + __int_as_float(y);
}
__device__ __forceinline__ float wave_sum64(float x) {
    x = dpp_add_f32<0x111>(x);   // row_shr:1
    x = dpp_add_f32<0x112>(x);   // row_shr:2
    x = dpp_add_f32<0x114>(x);   // row_shr:4
    x = dpp_add_f32<0x118>(x);   // row_shr:8
    x = dpp_add_f32<0x142>(x);   // row_bcast:15
    x = dpp_add_f32<0x143>(x);   // row_bcast:31 -> lane 63 = total
    return __int_as_float(__builtin_amdgcn_readlane(__float_as_int(x), 63));
}

// ---------------- measurement probes (output-inert; write to far ws) -------

// Exact replica of ece_hist's load pattern, compute stripped to 1 add/load.
// 4 passes so it lands in rocprof top-5 (> the ~113us harness fills).
__global__ __launch_bounds__(1024, 8)
void probe_pat(const float* __restrict__ logits, int N, float* __restrict__ sink)
{
    const int  tid  = threadIdx.x;
    const int  lane = tid & 63;
    const int  wv   = (blockIdx.x << 4) + (tid >> 6);
    const int  nwv  = gridDim.x << 4;
    const bool act  = lane < NHALF;
    const float2* base2 = reinterpret_cast<const float2*>(logits);

    float acc = 0.0f;
    for (int pass = 0; pass < 4; ++pass) {
        for (int row0 = wv * R; row0 < N; row0 += nwv * R) {
            const float2* rp = base2 + (size_t)row0 * NHALF + lane;
            #pragma unroll
            for (int r = 0; r < R; ++r) {
                float2 v = (act && row0 + r < N) ? rp[r * NHALF] : make_float2(0.f, 0.f);
                acc += v.x + v.y;
            }
        }
    }
    sink[blockIdx.x * 1024 + tid] = acc;   // keep loads live
}

// Dense linear 64-lane float4 stream over the same buffer, 5 passes.
__global__ __launch_bounds__(1024, 8)
void probe_lin(const float4* __restrict__ p, int n4, float* __restrict__ sink)
{
    const int gtid   = blockIdx.x * 1024 + threadIdx.x;
    const int stride = gridDim.x * 1024;
    float acc = 0.0f;
    for (int pass = 0; pass < 5; ++pass) {
        for (int i = gtid; i < n4; i += stride) {
            float4 v = p[i];
            acc += (v.x + v.y) + (v.z + v.w);
        }
    }
    sink[gtid] = acc;
}

// ---------------- production kernels (round-6 verbatim) --------------------

__global__ __launch_bounds__(1024, 8)
void ece_hist(const float* __restrict__ logits,
              const int* __restrict__ labels,
              int N,
              double* __restrict__ g_conf,
              unsigned int* __restrict__ g_acc)
{
    __shared__ float        s_conf[NSEG];
    __shared__ unsigned int s_acc[NSEG];

    const int tid = threadIdx.x;
    for (int i = tid; i < NSEG; i += 1024) { s_conf[i] = 0.0f; s_acc[i] = 0u; }
    __syncthreads();

    const int  lane = tid & 63;
    const int  wv   = (blockIdx.x << 4) + (tid >> 6);   // 16 waves/block
    const int  nwv  = gridDim.x << 4;
    const bool act  = lane < NHALF;                     // lanes 0..49 active

    float        conf0_a = 0.0f, conf0_b = 0.0f;
    unsigned int acc0_a  = 0u,   acc0_b  = 0u;

    const float2* base2 = reinterpret_cast<const float2*>(logits);

    for (int row0 = wv * R; row0 < N; row0 += nwv * R) {
        const bool full = (row0 + R <= N);
        float e0[R], e1[R], s[R];
        int   lbl[R];

        const float2* rp = base2 + (size_t)row0 * NHALF + lane;
        if (full) {
            #pragma unroll
            for (int r = 0; r < R; ++r) {
                float2 v = act ? rp[r * NHALF] : make_float2(0.0f, 0.0f);
                e0[r] = v.x; e1[r] = v.y;
            }
            int4 lb = *reinterpret_cast<const int4*>(labels + row0);
            lbl[0] = lb.x; lbl[1] = lb.y; lbl[2] = lb.z; lbl[3] = lb.w;
        } else {
            #pragma unroll
            for (int r = 0; r < R; ++r) {
                int row = min(row0 + r, N - 1);
                float2 v = act ? base2[(size_t)row * NHALF + lane] : make_float2(0.0f, 0.0f);
                e0[r] = v.x; e1[r] = v.y;
                lbl[r] = labels[row];
            }
        }

        #pragma unroll
        for (int r = 0; r < R; ++r) {
            e0[r] = act ? __expf(e0[r]) : 0.0f;
            e1[r] = act ? __expf(e1[r]) : 0.0f;
        }

        #pragma unroll
        for (int r = 0; r < R; ++r) s[r] = wave_sum64(e0[r] + e1[r]);

        #pragma unroll
        for (int r = 0; r < R; ++r) {
            if (!full && row0 + r >= N) break;
            const float inv    = __builtin_amdgcn_rcpf(s[r]);      // ~1 ulp
            const float thresh = s[r] * (1.0f / (float)NBINS);     // e > thresh <=> bin >= 1
            const int   lb     = lbl[r];
            const bool  mine   = (lane == (lb >> 1));
            const int   lbbit  = lb & 1;

            {
                float p0 = e0[r] * inv;
                if (e0[r] > thresh) {                  // rare: bin >= 1
                    int b0 = min((int)ceilf(p0 * (float)NBINS) - 1, NBINS - 1);
                    atomicAdd(&s_conf[(2 * lane) * NBINS + b0], p0);
                    if (mine && lbbit == 0) atomicAdd(&s_acc[(2 * lane) * NBINS + b0], 1u);
                } else {                               // hot: bin 0, register
                    conf0_a += p0;
                    if (mine && lbbit == 0) ++acc0_a;
                }
            }
            {
                float p1 = e1[r] * inv;
                if (e1[r] > thresh) {
                    int b1 = min((int)ceilf(p1 * (float)NBINS) - 1, NBINS - 1);
                    atomicAdd(&s_conf[(2 * lane + 1) * NBINS + b1], p1);
                    if (mine && lbbit == 1) atomicAdd(&s_acc[(2 * lane + 1) * NBINS + b1], 1u);
                } else {
                    conf0_b += p1;
                    if (mine && lbbit == 1) ++acc0_b;
                }
            }
        }
    }

    if (act) {
        atomicAdd(&s_conf[(2 * lane) * NBINS], conf0_a);
        if (acc0_a) atomicAdd(&s_acc[(2 * lane) * NBINS], acc0_a);
        atomicAdd(&s_conf[(2 * lane + 1) * NBINS], conf0_b);
        if (acc0_b) atomicAdd(&s_acc[(2 * lane + 1) * NBINS], acc0_b);
    }

    __syncthreads();
    const int rot = (blockIdx.x * 61) % NSEG;
    for (int i = tid; i < NSEG; i += 1024) {
        int j = i + rot; if (j >= NSEG) j -= NSEG;
        float        c = s_conf[j];
        unsigned int a = s_acc[j];
        if (c != 0.0f) atomicAdd(&g_conf[j], (double)c);
        if (a)         atomicAdd(&g_acc[j], a);
    }
}

__global__ void ece_final(const double* __restrict__ g_conf,
                          const unsigned int* __restrict__ g_acc,
                          float* __restrict__ out, double inv_nc)
{
    __shared__ double sh[16];
    double t = 0.0;
    for (int i = threadIdx.x; i < NSEG; i += blockDim.x)
        t += fabs(g_conf[i] - (double)g_acc[i]);
    #pragma unroll
    for (int off = 32; off; off >>= 1) t += __shfl_xor(t, off);
    const int lane = threadIdx.x & 63, w = threadIdx.x >> 6;
    if (lane == 0) sh[w] = t;
    __syncthreads();
    if (threadIdx.x == 0) {
        double tot = 0.0;
        const int nw = (int)(blockDim.x >> 6);
        for (int i = 0; i < nw; ++i) tot += sh[i];
        out[0] = (float)(tot * inv_nc);
    }
}

extern "C" void kernel_launch(void* const* d_in, const int* in_sizes, int n_in,
                              void* d_out, int out_size, void* d_ws, size_t ws_size,
                              hipStream_t stream)
{
    const float* logits = (const float*)d_in[0];
    const int*   labels = (const int*)d_in[1];
    const int N = in_sizes[1];   // labels count = row count

    double*       g_conf = (double*)d_ws;
    unsigned int* g_acc  = (unsigned int*)(g_conf + NSEG);
    // probe sinks live far away from the histogram region
    float* sink1 = (float*)((char*)d_ws + (1u << 20));
    float* sink2 = (float*)((char*)d_ws + (8u << 20));

    // --- measurement probes (do not affect d_out) ---
    probe_pat<<<512, 1024, 0, stream>>>(logits, N, sink1);
    probe_lin<<<512, 1024, 0, stream>>>((const float4*)logits,
                                        (N * NCLS) / 4, sink2);

    // --- production path (round-6 verbatim) ---
    (void)hipMemsetAsync(d_ws, 0, NSEG * sizeof(double) + NSEG * sizeof(unsigned int), stream);

    ece_hist<<<512, 1024, 0, stream>>>(logits, labels, N, g_conf, g_acc);

    const double inv_nc = 1.0 / ((double)N * (double)NCLS);
    ece_final<<<1, 256, 0, stream>>>(g_conf, g_acc, (float*)d_out, inv_nc);
}

// Round 12
// 79.017 us; speedup vs baseline: 3.9296x; 3.9296x over previous
//
#include <hip/hip_runtime.h>
#include <math.h>

#define NBINS 15
#define NCLS  100
#define NHALF 50               // float2 slots per row (2 classes per lane)
#define NSEG  (NBINS * NCLS)   // 1500
#define TROWS 128              // rows staged per block-tile (51.2 KB LDS)
#define NF4T  (TROWS * NCLS / 4)

// DPP-based wave64 sum on the VALU pipe (no DS ops). ctrl must be literal.
template <int CTRL>
__device__ __forceinline__ float dpp_add_f32(float x) {
    int y = __builtin_amdgcn_update_dpp(0, __float_as_int(x), CTRL, 0xf, 0xf, true);
    return x + __int_as_float(y);
}
__device__ __forceinline__ float wave_sum64(float x) {
    x = dpp_add_f32<0x111>(x);   // row_shr:1
    x = dpp_add_f32<0x112>(x);   // row_shr:2
    x = dpp_add_f32<0x114>(x);   // row_shr:4
    x = dpp_add_f32<0x118>(x);   // row_shr:8
    x = dpp_add_f32<0x142>(x);   // row_bcast:15
    x = dpp_add_f32<0x143>(x);   // row_bcast:31 -> lane 63 = total
    return __int_as_float(__builtin_amdgcn_readlane(__float_as_int(x), 63));
}

// Block-tile staged: dense float4 global->LDS (probe_lin pattern), then
// round-6 per-row compute/epilogue reading float2 from LDS.
__global__ __launch_bounds__(1024, 8)
void ece_hist(const float* __restrict__ logits,
              const int* __restrict__ labels,
              int N,
              double* __restrict__ g_conf,
              unsigned int* __restrict__ g_acc)
{
    __shared__ __align__(16) float s_tile[TROWS * NCLS];   // 51200 B
    __shared__ float        s_conf[NSEG];
    __shared__ unsigned int s_acc[NSEG];

    const int tid = threadIdx.x;
    for (int i = tid; i < NSEG; i += 1024) { s_conf[i] = 0.0f; s_acc[i] = 0u; }
    // (first tile's post-stage barrier orders this before any histogram use)

    const int  lane = tid & 63;
    const int  w    = tid >> 6;          // wave 0..15; rows w*8..w*8+7 of tile
    const bool act  = lane < NHALF;

    float        conf0_a = 0.0f, conf0_b = 0.0f;
    unsigned int acc0_a  = 0u,   acc0_b  = 0u;

    const float4* g4 = reinterpret_cast<const float4*>(logits);
    float4*       t4 = reinterpret_cast<float4*>(s_tile);
    const float2* s2 = reinterpret_cast<const float2*>(s_tile);

    const int ntiles = (N + TROWS - 1) / TROWS;

    for (int tile = blockIdx.x; tile < ntiles; tile += gridDim.x) {
        const int start = tile * TROWS;
        const int rows  = min(TROWS, N - start);
        const int nf4   = rows * (NCLS / 4);

        __syncthreads();                 // prior tile's readers done
        // dense, fully-coalesced 16B/lane staging (all 64 lanes)
        const size_t gbase = (size_t)start * (NCLS / 4);
        for (int i = tid; i < nf4; i += 1024)
            t4[i] = g4[gbase + i];
        __syncthreads();                 // tile visible

        #pragma unroll
        for (int half = 0; half < 2; ++half) {
            const int r0 = w * 8 + half * 4;          // row within tile
            if (r0 >= rows) break;
            const bool full = (r0 + 4 <= rows);
            float e0[4], e1[4], s[4];
            int   lbl[4];

            if (full) {
                #pragma unroll
                for (int r = 0; r < 4; ++r) {
                    float2 v = act ? s2[(r0 + r) * NHALF + lane] : make_float2(0.f, 0.f);
                    e0[r] = v.x; e1[r] = v.y;
                }
                const int4 lb = *reinterpret_cast<const int4*>(labels + start + r0);
                lbl[0] = lb.x; lbl[1] = lb.y; lbl[2] = lb.z; lbl[3] = lb.w;
            } else {
                #pragma unroll
                for (int r = 0; r < 4; ++r) {
                    int rr = min(r0 + r, rows - 1);
                    float2 v = act ? s2[rr * NHALF + lane] : make_float2(0.f, 0.f);
                    e0[r] = v.x; e1[r] = v.y;
                    lbl[r] = labels[start + rr];
                }
            }

            #pragma unroll
            for (int r = 0; r < 4; ++r) {
                e0[r] = act ? __expf(e0[r]) : 0.0f;
                e1[r] = act ? __expf(e1[r]) : 0.0f;
            }

            #pragma unroll
            for (int r = 0; r < 4; ++r) s[r] = wave_sum64(e0[r] + e1[r]);

            #pragma unroll
            for (int r = 0; r < 4; ++r) {
                if (!full && r0 + r >= rows) break;
                const float inv    = __builtin_amdgcn_rcpf(s[r]);   // ~1 ulp
                const float thresh = s[r] * (1.0f / (float)NBINS);  // e > thresh <=> bin >= 1
                const int   lb     = lbl[r];
                const bool  mine   = (lane == (lb >> 1));
                const int   lbbit  = lb & 1;

                {
                    float p0 = e0[r] * inv;
                    if (e0[r] > thresh) {              // rare: bin >= 1
                        int b0 = min((int)ceilf(p0 * (float)NBINS) - 1, NBINS - 1);
                        atomicAdd(&s_conf[(2 * lane) * NBINS + b0], p0);
                        if (mine && lbbit == 0) atomicAdd(&s_acc[(2 * lane) * NBINS + b0], 1u);
                    } else {                           // hot: bin 0, register
                        conf0_a += p0;
                        if (mine && lbbit == 0) ++acc0_a;
                    }
                }
                {
                    float p1 = e1[r] * inv;
                    if (e1[r] > thresh) {
                        int b1 = min((int)ceilf(p1 * (float)NBINS) - 1, NBINS - 1);
                        atomicAdd(&s_conf[(2 * lane + 1) * NBINS + b1], p1);
                        if (mine && lbbit == 1) atomicAdd(&s_acc[(2 * lane + 1) * NBINS + b1], 1u);
                    } else {
                        conf0_b += p1;
                        if (mine && lbbit == 1) ++acc0_b;
                    }
                }
            }
        }
    }

    // Flush per-lane register accumulators into the LDS histogram (once).
    if (act) {
        atomicAdd(&s_conf[(2 * lane) * NBINS], conf0_a);
        if (acc0_a) atomicAdd(&s_acc[(2 * lane) * NBINS], acc0_a);
        atomicAdd(&s_conf[(2 * lane + 1) * NBINS], conf0_b);
        if (acc0_b) atomicAdd(&s_acc[(2 * lane + 1) * NBINS], acc0_b);
    }

    __syncthreads();
    // Flush block partials; rotate start so concurrent blocks hit different
    // global addresses.
    const int rot = (blockIdx.x * 61) % NSEG;
    for (int i = tid; i < NSEG; i += 1024) {
        int j = i + rot; if (j >= NSEG) j -= NSEG;
        float        c = s_conf[j];
        unsigned int a = s_acc[j];
        if (c != 0.0f) atomicAdd(&g_conf[j], (double)c);
        if (a)         atomicAdd(&g_acc[j], a);
    }
}

// result = sum_j |conf_sum[j] - acc_sum[j]| / (N*C)
__global__ void ece_final(const double* __restrict__ g_conf,
                          const unsigned int* __restrict__ g_acc,
                          float* __restrict__ out, double inv_nc)
{
    __shared__ double sh[16];
    double t = 0.0;
    for (int i = threadIdx.x; i < NSEG; i += blockDim.x)
        t += fabs(g_conf[i] - (double)g_acc[i]);
    #pragma unroll
    for (int off = 32; off; off >>= 1) t += __shfl_xor(t, off);
    const int lane = threadIdx.x & 63, w = threadIdx.x >> 6;
    if (lane == 0) sh[w] = t;
    __syncthreads();
    if (threadIdx.x == 0) {
        double tot = 0.0;
        const int nw = (int)(blockDim.x >> 6);
        for (int i = 0; i < nw; ++i) tot += sh[i];
        out[0] = (float)(tot * inv_nc);
    }
}

extern "C" void kernel_launch(void* const* d_in, const int* in_sizes, int n_in,
                              void* d_out, int out_size, void* d_ws, size_t ws_size,
                              hipStream_t stream)
{
    const float* logits = (const float*)d_in[0];
    const int*   labels = (const int*)d_in[1];
    const int N = in_sizes[1];   // labels count = row count

    double*       g_conf = (double*)d_ws;
    unsigned int* g_acc  = (unsigned int*)(g_conf + NSEG);

    (void)hipMemsetAsync(d_ws, 0, NSEG * sizeof(double) + NSEG * sizeof(unsigned int), stream);

    ece_hist<<<1024, 1024, 0, stream>>>(logits, labels, N, g_conf, g_acc);

    const double inv_nc = 1.0 / ((double)N * (double)NCLS);
    ece_final<<<1, 256, 0, stream>>>(g_conf, g_acc, (float*)d_out, inv_nc);
}

// Round 13
// 59.750 us; speedup vs baseline: 5.1968x; 1.3225x over previous
//
#include <hip/hip_runtime.h>
#include <math.h>

#define NBINS 15
#define NCLS  100
#define NSEG  (NBINS * NCLS)   // 1500
#define RP    2                // row-pairs per wave per iteration (4 rows)

// DPP partial chain: shr 1/2/4/8 + row_bcast:15 (NO bcast31) ->
// lane 31 = sum(lanes 0..31), lane 63 = sum(lanes 32..63).
template <int CTRL>
__device__ __forceinline__ float dpp_add_f32(float x) {
    int y = __builtin_amdgcn_update_dpp(0, __float_as_int(x), CTRL, 0xf, 0xf, true);
    return x + __int_as_float(y);
}
__device__ __forceinline__ float half_sums(float x) {   // returns vector reg; extract via readlane 31/63
    x = dpp_add_f32<0x111>(x);   // row_shr:1
    x = dpp_add_f32<0x112>(x);   // row_shr:2
    x = dpp_add_f32<0x114>(x);   // row_shr:4
    x = dpp_add_f32<0x118>(x);   // row_shr:8
    x = dpp_add_f32<0x142>(x);   // row_bcast:15 -> lane31 = S(0..31), lane63 = S(32..63)
    return x;
}

// Row-pair scheme: one float4 load covers 800B = rows (r, r+1).
// lane l<25        -> row r,   classes 4l..4l+3
// lane 32+l (l<25) -> row r+1, classes 4l..4l+3
__global__ __launch_bounds__(1024, 8)
void ece_hist(const float* __restrict__ logits,
              const int* __restrict__ labels,
              int N,
              double* __restrict__ g_conf,
              unsigned int* __restrict__ g_acc)
{
    __shared__ float        s_conf[NSEG];
    __shared__ unsigned int s_acc[NSEG];

    const int tid = threadIdx.x;
    for (int i = tid; i < NSEG; i += 1024) { s_conf[i] = 0.0f; s_acc[i] = 0u; }
    __syncthreads();

    const int  lane  = tid & 63;
    const int  hlane = lane & 31;            // position within half-wave
    const bool hiW   = lane >= 32;           // high half handles odd row of pair
    const bool act   = hlane < 25;
    const int  wv    = (blockIdx.x << 4) + (tid >> 6);
    const int  nwv   = gridDim.x << 4;

    // Register accumulators for bin 0 of this lane's 4 classes (4*hlane+k).
    float        c0 = 0.f, c1 = 0.f, c2 = 0.f, c3 = 0.f;
    unsigned int a0 = 0u,  a1 = 0u,  a2 = 0u,  a3 = 0u;

    const float4* g4 = reinterpret_cast<const float4*>(logits);
    // float4 index within a row-pair: 0..49; this lane's slot:
    const int laneoff = (hiW ? 25 : 0) + hlane;   // 0..24 low rows, 25..49 high rows

    const int ROWS = RP * 2;                 // rows per iteration = 4
    for (int row0 = wv * ROWS; row0 < N; row0 += nwv * ROWS) {
        if (row0 + ROWS <= N) {
            float e[RP][4], xs[RP];
            // one dense 800B load per pair
            #pragma unroll
            for (int p = 0; p < RP; ++p) {
                const size_t idx = (size_t)(row0 + 2 * p) * 25 + laneoff;
                float4 v = act ? g4[idx] : make_float4(0.f, 0.f, 0.f, 0.f);
                e[p][0] = v.x; e[p][1] = v.y; e[p][2] = v.z; e[p][3] = v.w;
            }
            const int4 lb4 = *reinterpret_cast<const int4*>(labels + row0);
            int lbA[RP], lbB[RP];
            lbA[0] = lb4.x; lbB[0] = lb4.y; lbA[1] = lb4.z; lbB[1] = lb4.w;

            #pragma unroll
            for (int p = 0; p < RP; ++p) {
                #pragma unroll
                for (int k = 0; k < 4; ++k)
                    e[p][k] = act ? __expf(e[p][k]) : 0.0f;
            }
            #pragma unroll
            for (int p = 0; p < RP; ++p)
                xs[p] = half_sums((e[p][0] + e[p][1]) + (e[p][2] + e[p][3]));

            #pragma unroll
            for (int p = 0; p < RP; ++p) {
                const float sA = __int_as_float(__builtin_amdgcn_readlane(__float_as_int(xs[p]), 31));
                const float sB = __int_as_float(__builtin_amdgcn_readlane(__float_as_int(xs[p]), 63));
                const float sm   = hiW ? sB : sA;          // my row's sum
                const float inv  = __builtin_amdgcn_rcpf(sm);
                const float thr  = sm * (1.0f / (float)NBINS);
                const int   lb   = hiW ? lbB[p] : lbA[p];
                const bool  mine = (hlane == (lb >> 2));
                const int   slot = lb & 3;

                const float p0 = e[p][0] * inv, p1 = e[p][1] * inv;
                const float p2 = e[p][2] * inv, p3 = e[p][3] * inv;
                const bool  r0 = e[p][0] > thr, r1 = e[p][1] > thr;
                const bool  r2 = e[p][2] > thr, r3 = e[p][3] > thr;

                c0 += r0 ? 0.0f : p0;
                c1 += r1 ? 0.0f : p1;
                c2 += r2 ? 0.0f : p2;
                c3 += r3 ? 0.0f : p3;
                if (mine) {
                    a0 += (slot == 0 && !r0) ? 1u : 0u;
                    a1 += (slot == 1 && !r1) ? 1u : 0u;
                    a2 += (slot == 2 && !r2) ? 1u : 0u;
                    a3 += (slot == 3 && !r3) ? 1u : 0u;
                }
                if (r0 | r1 | r2 | r3) {                   // rare, exec-masked
                    #pragma unroll
                    for (int k = 0; k < 4; ++k) {
                        if (e[p][k] > thr) {
                            const float pk = e[p][k] * inv;
                            int b = min((int)ceilf(pk * (float)NBINS) - 1, NBINS - 1);
                            atomicAdd(&s_conf[(4 * hlane + k) * NBINS + b], pk);
                            if (mine && slot == k)
                                atomicAdd(&s_acc[(4 * hlane + k) * NBINS + b], 1u);
                        }
                    }
                }
            }
        } else {
            // tail fallback (not taken when N%4==0): per-row, low half only
            for (int r = 0; r < ROWS && row0 + r < N; ++r) {
                const int row = row0 + r;
                const size_t idx = (size_t)row * 25 + hlane;
                float4 v = (act && !hiW) ? g4[idx] : make_float4(0.f, 0.f, 0.f, 0.f);
                float ek[4];
                #pragma unroll
                for (int k = 0; k < 4; ++k)
                    ek[k] = (act && !hiW) ? __expf(k == 0 ? v.x : k == 1 ? v.y : k == 2 ? v.z : v.w) : 0.0f;
                float xsum = half_sums((ek[0] + ek[1]) + (ek[2] + ek[3]));
                const float sm  = __int_as_float(__builtin_amdgcn_readlane(__float_as_int(xsum), 31));
                const float inv = __builtin_amdgcn_rcpf(sm);
                const float thr = sm * (1.0f / (float)NBINS);
                if (act && !hiW) {
                    const int  lb   = labels[row];
                    const bool mine = (hlane == (lb >> 2));
                    const int  slot = lb & 3;
                    #pragma unroll
                    for (int k = 0; k < 4; ++k) {
                        const float pk = ek[k] * inv;
                        if (ek[k] > thr) {
                            int b = min((int)ceilf(pk * (float)NBINS) - 1, NBINS - 1);
                            atomicAdd(&s_conf[(4 * hlane + k) * NBINS + b], pk);
                            if (mine && slot == k) atomicAdd(&s_acc[(4 * hlane + k) * NBINS + b], 1u);
                        } else {
                            if (k == 0) c0 += pk; else if (k == 1) c1 += pk;
                            else if (k == 2) c2 += pk; else c3 += pk;
                            if (mine && slot == k) {
                                if (k == 0) ++a0; else if (k == 1) ++a1;
                                else if (k == 2) ++a2; else ++a3;
                            }
                        }
                    }
                }
            }
        }
    }

    // Flush per-lane register accumulators (both halves own the same classes;
    // LDS atomics merge them).
    if (act) {
        atomicAdd(&s_conf[(4 * hlane + 0) * NBINS], c0);
        atomicAdd(&s_conf[(4 * hlane + 1) * NBINS], c1);
        atomicAdd(&s_conf[(4 * hlane + 2) * NBINS], c2);
        atomicAdd(&s_conf[(4 * hlane + 3) * NBINS], c3);
        if (a0) atomicAdd(&s_acc[(4 * hlane + 0) * NBINS], a0);
        if (a1) atomicAdd(&s_acc[(4 * hlane + 1) * NBINS], a1);
        if (a2) atomicAdd(&s_acc[(4 * hlane + 2) * NBINS], a2);
        if (a3) atomicAdd(&s_acc[(4 * hlane + 3) * NBINS], a3);
    }

    __syncthreads();
    const int rot = (blockIdx.x * 61) % NSEG;
    for (int i = tid; i < NSEG; i += 1024) {
        int j = i + rot; if (j >= NSEG) j -= NSEG;
        float        c = s_conf[j];
        unsigned int a = s_acc[j];
        if (c != 0.0f) atomicAdd(&g_conf[j], (double)c);
        if (a)         atomicAdd(&g_acc[j], a);
    }
}

// result = sum_j |conf_sum[j] - acc_sum[j]| / (N*C)
__global__ void ece_final(const double* __restrict__ g_conf,
                          const unsigned int* __restrict__ g_acc,
                          float* __restrict__ out, double inv_nc)
{
    __shared__ double sh[16];
    double t = 0.0;
    for (int i = threadIdx.x; i < NSEG; i += blockDim.x)
        t += fabs(g_conf[i] - (double)g_acc[i]);
    #pragma unroll
    for (int off = 32; off; off >>= 1) t += __shfl_xor(t, off);
    const int lane = threadIdx.x & 63, w = threadIdx.x >> 6;
    if (lane == 0) sh[w] = t;
    __syncthreads();
    if (threadIdx.x == 0) {
        double tot = 0.0;
        const int nw = (int)(blockDim.x >> 6);
        for (int i = 0; i < nw; ++i) tot += sh[i];
        out[0] = (float)(tot * inv_nc);
    }
}

extern "C" void kernel_launch(void* const* d_in, const int* in_sizes, int n_in,
                              void* d_out, int out_size, void* d_ws, size_t ws_size,
                              hipStream_t stream)
{
    const float* logits = (const float*)d_in[0];
    const int*   labels = (const int*)d_in[1];
    const int N = in_sizes[1];   // labels count = row count

    double*       g_conf = (double*)d_ws;
    unsigned int* g_acc  = (unsigned int*)(g_conf + NSEG);

    (void)hipMemsetAsync(d_ws, 0, NSEG * sizeof(double) + NSEG * sizeof(unsigned int), stream);

    ece_hist<<<512, 1024, 0, stream>>>(logits, labels, N, g_conf, g_acc);

    const double inv_nc = 1.0 / ((double)N * (double)NCLS);
    ece_final<<<1, 256, 0, stream>>>(g_conf, g_acc, (float*)d_out, inv_nc);
}